// Round 7
// baseline (145.247 us; speedup 1.0000x reference)
//
#include <hip/hip_runtime.h>
#include <stdint.h>

// out = conv3x3_zeropad(s, W_eff), s = 3x3 reflect-pad box sum of x (B=16,C=64,H=W=128)
// R12: fused kernel, 2-BLOCKS/CU PHASE OVERLAP. R6 (4-row tile, 101KB LDS,
// 1 block/CU) serialized stage->MFMA->epilogue per CU (55us vs 21us BW floor,
// all pipes <30%). Tile halved to 2 out-rows x 128 w: LDS 67.6KB -> 2 resident
// blocks alternate phases (reads overlap writes). Wave shape, swizzle, MFMA
// loop, epilogue all byte-identical to verified R6. Staging = coalesced
// (w4, 8-ch) threads, verified shfl horizontal, full 16B-unit b128 writes.
// Halo x-rows (x3 raw) are L3-absorbed (R6 measured FETCH=65MB=minimal).

#define THETA 0.7f

typedef __attribute__((ext_vector_type(8))) short bf16x8;
typedef __attribute__((ext_vector_type(16))) float f32x16;

__device__ inline unsigned short f2bf(float f) {
    unsigned u = __float_as_uint(f);
    u = (u + 0x7FFFu + ((u >> 16) & 1u)) >> 16;   // RNE
    return (unsigned short)u;
}

// ---------------------------------------------------------------------------
// Kernel 1: W_eff -> Wt2 bf16, lane-contiguous MFMA-A layout (verified):
// Wt2[(((tap*4+ic)*2+mf)*64 + lane)*8 + j] = W_eff[o][ch][tap]
//   o = mf*32 + (lane&31), ch = ic*16 + (lane>>5)*8 + j
// ---------------------------------------------------------------------------
__global__ void weff_kernel(const float* __restrict__ W, unsigned short* __restrict__ Wt2) {
    int t = blockIdx.x * blockDim.x + threadIdx.x;   // 512 threads
    if (t >= 512) return;
    int o = t >> 3;
    int ch8 = t & 7;
    int c0 = ch8 * 8;
    int ic = ch8 >> 1;
    int mf = o >> 5;
    int lane = (o & 31) | ((ch8 & 1) << 5);

    float v[8][9];
    float tsum[8];
#pragma unroll
    for (int j = 0; j < 8; j++) {
        const float* w = W + ((size_t)o * 64 + c0 + j) * 9;
        float sum = 0.f;
#pragma unroll
        for (int k = 0; k < 9; k++) { v[j][k] = w[k]; sum += v[j][k]; }
        tsum[j] = sum;
    }
#pragma unroll
    for (int tap = 0; tap < 9; tap++) {
        unsigned short* dst = Wt2 + (((size_t)(tap * 4 + ic) * 2 + mf) * 64 + lane) * 8;
#pragma unroll
        for (int j = 0; j < 8; j++) {
            float val = v[j][tap] - ((tap == 4) ? THETA * tsum[j] : 0.f);
            dst[j] = f2bf(val);
        }
    }
}

// ---------------------------------------------------------------------------
// Kernel 2: fused boxsum + implicit-GEMM conv, mfma_f32_32x32x16_bf16.
// Block = (b, 2 out-rows, full 128 px), 256 thr / 4 waves; wave = 1 row x
// 64 px (whalf) x 64 o (mf=2 x nf=2, acc[2][2] of f32x16).
// LDS s-tile: [4 rows][132 slots][64 c] bf16 = 67584 B -> 2 blocks/CU.
// slot = w+1 (slots 0/129 conv zero-pad); 16B units XOR-swizzled
// p = (c>>3) ^ (slot&7). Grid 1024 = 16 b x 64 strips (h0 = strip*2).
// ---------------------------------------------------------------------------
__global__ __launch_bounds__(256, 2) void fused_kernel(const float* __restrict__ x,
                                                       const unsigned short* __restrict__ Wt2,
                                                       float* __restrict__ out) {
    __shared__ __align__(16) unsigned short sS[4 * 132 * 64];   // 67584 B

    int bid = blockIdx.x;
    int b = bid >> 6;
    int h0 = (bid & 63) * 2;
    int tid = threadIdx.x;
    int lane = tid & 63;
    int wv = tid >> 6;          // 0..3
    int n32 = lane & 31;
    int q2 = lane >> 5;
    int orow = wv >> 1;         // out row within tile (0..1)
    int whalf = wv & 1;         // which 64-px half

    // zero-pad slots 0 (w=-1) and 129 (w=128), rows 0..3: 64 x 16B
    int4 z = make_int4(0, 0, 0, 0);
    if (tid < 64) {
        int rr = tid >> 4;
        int sl = ((tid >> 3) & 1) ? 129 : 0;
        int g = tid & 7;
        *(int4*)((char*)sS + ((size_t)(rr * 132 + sl) * 8 + g) * 16) = z;
    }
    // zero OOB rows at image edges (staging skips them); row = 1056 int4
    if (h0 == 0)
        for (int i = tid; i < 1056; i += 256) *(int4*)((char*)sS + (size_t)i * 16) = z;
    if (h0 == 126)
        for (int i = tid; i < 1056; i += 256) *(int4*)((char*)sS + (size_t)(3168 + i) * 16) = z;

    // A-frags for tap 0: issued early, consumed post-barrier
    bf16x8 Af[8], An[8];
#pragma unroll
    for (int ic = 0; ic < 4; ic++)
#pragma unroll
        for (int mf = 0; mf < 2; mf++)
            Af[ic * 2 + mf] = *(const bf16x8*)(Wt2 + (((size_t)(0 * 4 + ic) * 2 + mf) * 64 + lane) * 8);

    // ---- coalesced staging: thread = (w4 = tid&31, cg = tid>>5 -> 8 ch) ----
    {
        int w4 = tid & 31;
        int cg = tid >> 5;          // 0..7, unit index = cg
        const float* xp = x + ((size_t)(b * 64 + cg * 8)) * 16384 + w4 * 4;

        int hgf = (h0 == 0) ? 0 : h0 - 1;         // first valid s-row
        int hm = (hgf == 0) ? 1 : hgf - 1;        // vertical reflect up
        float4 A[8], Bv[8], C[8];
#pragma unroll
        for (int cc = 0; cc < 8; cc++) {
            A[cc]  = *(const float4*)(xp + (size_t)cc * 16384 + (size_t)hm * 128);
            Bv[cc] = *(const float4*)(xp + (size_t)cc * 16384 + (size_t)hgf * 128);
            C[cc]  = *(const float4*)(xp + (size_t)cc * 16384 + (size_t)(hgf + 1) * 128);
        }

#pragma unroll
        for (int rr = 0; rr < 4; rr++) {
            int hg = h0 - 1 + rr;
            if (hg < 0 || hg > 127) continue;     // block-uniform skip (pre-zeroed)

            float4 Cn[8];
            if (rr < 3) {
                int hn = hg + 2;
                if (hn > 127) hn = 126;           // vertical reflect down
#pragma unroll
                for (int cc = 0; cc < 8; cc++)
                    Cn[cc] = *(const float4*)(xp + (size_t)cc * 16384 + (size_t)hn * 128);
            }

            unsigned short res[8][4];   // [cc][k]
#pragma unroll
            for (int cc = 0; cc < 8; cc++) {
                float4 vs;
                vs.x = A[cc].x + Bv[cc].x + C[cc].x;
                vs.y = A[cc].y + Bv[cc].y + C[cc].y;
                vs.z = A[cc].z + Bv[cc].z + C[cc].z;
                vs.w = A[cc].w + Bv[cc].w + C[cc].w;
                float L = __shfl_up(vs.w, 1, 32);
                float R = __shfl_down(vs.x, 1, 32);
                float sx = (w4 == 0) ? vs.x + 2.f * vs.y : L + vs.x + vs.y;
                float sy = vs.x + vs.y + vs.z;
                float sz = vs.y + vs.z + vs.w;
                float sw_ = (w4 == 31) ? 2.f * vs.z + vs.w : vs.z + vs.w + R;
                res[cc][0] = f2bf(sx);
                res[cc][1] = f2bf(sy);
                res[cc][2] = f2bf(sz);
                res[cc][3] = f2bf(sw_);
            }
            // write 4 full 16B units (8 channels packed) into swizzled slots
#pragma unroll
            for (int k = 0; k < 4; k++) {
                int slot = w4 * 4 + k + 1;        // w = w4*4+k -> slot w+1
                int p = cg ^ (slot & 7);
                int4 o4;
                o4.x = (int)res[0][k] | ((int)res[1][k] << 16);
                o4.y = (int)res[2][k] | ((int)res[3][k] << 16);
                o4.z = (int)res[4][k] | ((int)res[5][k] << 16);
                o4.w = (int)res[6][k] | ((int)res[7][k] << 16);
                *(int4*)(sS + (size_t)(rr * 132 + slot) * 64 + p * 8) = o4;
            }
            if (rr < 3) {
#pragma unroll
                for (int cc = 0; cc < 8; cc++) { A[cc] = Bv[cc]; Bv[cc] = C[cc]; C[cc] = Cn[cc]; }
            }
        }
    }
    __syncthreads();

    // B LDS offsets (shorts) per (kx, ic); add (orow+ky)*8448 + nf*2048
    int p0[3][4];
#pragma unroll
    for (int kx = 0; kx < 3; kx++)
#pragma unroll
        for (int ic = 0; ic < 4; ic++) {
            int slot = n32 + kx + whalf * 64;
            int g = (ic * 2 + q2) ^ (slot & 7);   // (slot+64)&7 == slot&7
            p0[kx][ic] = slot * 64 + g * 8;
        }

    f32x16 acc[2][2];
#pragma unroll
    for (int mf = 0; mf < 2; mf++)
#pragma unroll
        for (int nf = 0; nf < 2; nf++)
#pragma unroll
            for (int r = 0; r < 16; r++) acc[mf][nf][r] = 0.f;

#pragma unroll
    for (int tap = 0; tap < 9; tap++) {
        int ky = tap / 3, kx = tap % 3;
        if (tap < 8) {
#pragma unroll
            for (int ic = 0; ic < 4; ic++)
#pragma unroll
                for (int mf = 0; mf < 2; mf++)
                    An[ic * 2 + mf] = *(const bf16x8*)(Wt2 + (((size_t)((tap + 1) * 4 + ic) * 2 + mf) * 64 + lane) * 8);
        }
#pragma unroll
        for (int ic = 0; ic < 4; ic++) {
            const unsigned short* bp = sS + (size_t)(orow + ky) * 8448 + p0[kx][ic];
            bf16x8 b0 = *(const bf16x8*)(bp);
            bf16x8 b1 = *(const bf16x8*)(bp + 2048);
            acc[0][0] = __builtin_amdgcn_mfma_f32_32x32x16_bf16(Af[ic * 2 + 0], b0, acc[0][0], 0, 0, 0);
            acc[0][1] = __builtin_amdgcn_mfma_f32_32x32x16_bf16(Af[ic * 2 + 0], b1, acc[0][1], 0, 0, 0);
            acc[1][0] = __builtin_amdgcn_mfma_f32_32x32x16_bf16(Af[ic * 2 + 1], b0, acc[1][0], 0, 0, 0);
            acc[1][1] = __builtin_amdgcn_mfma_f32_32x32x16_bf16(Af[ic * 2 + 1], b1, acc[1][1], 0, 0, 0);
        }
        if (tap < 8) {
#pragma unroll
            for (int k = 0; k < 8; k++) Af[k] = An[k];
        }
    }

    // epilogue: 32x32 C/D layout col=lane&31 (pixel), row=(r&3)+8*(r>>2)+4*q2 (o)
    float* ob = out + ((size_t)b * 64) * 16384 + (size_t)(h0 + orow) * 128 + whalf * 64;
#pragma unroll
    for (int mf = 0; mf < 2; mf++)
#pragma unroll
        for (int nf = 0; nf < 2; nf++)
#pragma unroll
            for (int r = 0; r < 16; r++) {
                int o = mf * 32 + (r & 3) + 8 * (r >> 2) + 4 * q2;
                ob[(size_t)o * 16384 + nf * 32 + n32] = acc[mf][nf][r];
            }
}

// ---------------------------------------------------------------------------
extern "C" void kernel_launch(void* const* d_in, const int* in_sizes, int n_in,
                              void* d_out, int out_size, void* d_ws, size_t ws_size,
                              hipStream_t stream) {
    const float* x = (const float*)d_in[0];   // [16][64][128][128] fp32
    const float* W = (const float*)d_in[1];   // [64][64][3][3] fp32
    float* outp = (float*)d_out;

    // ws: Wt2 bf16 (73728 B); no global s intermediate
    unsigned short* Wt2 = (unsigned short*)d_ws;

    weff_kernel<<<2, 256, 0, stream>>>(W, Wt2);
    fused_kernel<<<1024, 256, 0, stream>>>(x, Wt2, outp);
}

// Round 8
// 141.171 us; speedup vs baseline: 1.0289x; 1.0289x over previous
//
#include <hip/hip_runtime.h>
#include <stdint.h>

// out = conv3x3_zeropad(s, W_eff), s = 3x3 reflect-pad box sum of x (B=16,C=64,H=W=128)
// R13: OCCUPANCY fix. All fused rounds ran 8 waves/CU (2/SIMD) -> issue-starved
// (Occupancy 17%, all pipes <30%, 78% stall). Same R7 tile (2 out-rows x 128w,
// [4][132][64] LDS = 67.6KB, 2 blocks/CU) but 512 thr / 8 waves per block:
// wave = 1 row x 64 px x 32 o (ohalf splits former mf), acc[2], Af[4],
// 72 MFMA/wave -> 16 waves/CU = 4/SIMD. Staging = R6-verified 512-thr pattern.
// Swizzle / B-reads / epilogue = verified math restricted to one mf.

#define THETA 0.7f

typedef __attribute__((ext_vector_type(8))) short bf16x8;
typedef __attribute__((ext_vector_type(16))) float f32x16;

__device__ inline unsigned short f2bf(float f) {
    unsigned u = __float_as_uint(f);
    u = (u + 0x7FFFu + ((u >> 16) & 1u)) >> 16;   // RNE
    return (unsigned short)u;
}

// ---------------------------------------------------------------------------
// Kernel 1: W_eff -> Wt2 bf16, lane-contiguous MFMA-A layout (verified):
// Wt2[(((tap*4+ic)*2+mf)*64 + lane)*8 + j] = W_eff[o][ch][tap]
//   o = mf*32 + (lane&31), ch = ic*16 + (lane>>5)*8 + j
// ---------------------------------------------------------------------------
__global__ void weff_kernel(const float* __restrict__ W, unsigned short* __restrict__ Wt2) {
    int t = blockIdx.x * blockDim.x + threadIdx.x;   // 512 threads
    if (t >= 512) return;
    int o = t >> 3;
    int ch8 = t & 7;
    int c0 = ch8 * 8;
    int ic = ch8 >> 1;
    int mf = o >> 5;
    int lane = (o & 31) | ((ch8 & 1) << 5);

    float v[8][9];
    float tsum[8];
#pragma unroll
    for (int j = 0; j < 8; j++) {
        const float* w = W + ((size_t)o * 64 + c0 + j) * 9;
        float sum = 0.f;
#pragma unroll
        for (int k = 0; k < 9; k++) { v[j][k] = w[k]; sum += v[j][k]; }
        tsum[j] = sum;
    }
#pragma unroll
    for (int tap = 0; tap < 9; tap++) {
        unsigned short* dst = Wt2 + (((size_t)(tap * 4 + ic) * 2 + mf) * 64 + lane) * 8;
#pragma unroll
        for (int j = 0; j < 8; j++) {
            float val = v[j][tap] - ((tap == 4) ? THETA * tsum[j] : 0.f);
            dst[j] = f2bf(val);
        }
    }
}

// ---------------------------------------------------------------------------
// Kernel 2: fused boxsum + implicit-GEMM conv, mfma_f32_32x32x16_bf16.
// Block = (b, 2 out-rows, full 128 px), 512 thr / 8 waves; wave =
// (ohalf = wv>>2, orow = (wv>>1)&1, whalf = wv&1): 1 row x 64 px x 32 o,
// acc[2] of f32x16, Af[4] (one A-frag per ic), 72 MFMA.
// LDS s-tile: [4 rows][132 slots][64 c] bf16 = 67584 B -> 2 blocks/CU
// = 16 waves/CU = 4/SIMD. slot = w+1 (slots 0/129 conv zero-pad);
// 16B units XOR-swizzled p = (c>>3) ^ (slot&7).
// Grid 1024 = 16 b x 64 strips (h0 = strip*2).
// ---------------------------------------------------------------------------
__global__ __launch_bounds__(512, 4) void fused_kernel(const float* __restrict__ x,
                                                       const unsigned short* __restrict__ Wt2,
                                                       float* __restrict__ out) {
    __shared__ __align__(16) unsigned short sS[4 * 132 * 64];   // 67584 B

    int bid = blockIdx.x;
    int b = bid >> 6;
    int h0 = (bid & 63) * 2;
    int tid = threadIdx.x;
    int lane = tid & 63;
    int wv = tid >> 6;          // 0..7
    int n32 = lane & 31;
    int q2 = lane >> 5;
    int ohalf = wv >> 2;        // which 32 output channels
    int orow = (wv >> 1) & 1;   // out row within tile
    int whalf = wv & 1;         // which 64-px half

    // zero-pad slots 0 (w=-1) and 129 (w=128), rows 0..3: 64 x 16B
    int4 z = make_int4(0, 0, 0, 0);
    if (tid < 64) {
        int rr = tid >> 4;
        int sl = ((tid >> 3) & 1) ? 129 : 0;
        int g = tid & 7;
        *(int4*)((char*)sS + ((size_t)(rr * 132 + sl) * 8 + g) * 16) = z;
    }
    // zero OOB rows at image edges (staging skips them); row = 1056 int4
    if (h0 == 0)
        for (int i = tid; i < 1056; i += 512) *(int4*)((char*)sS + (size_t)i * 16) = z;
    if (h0 == 126)
        for (int i = tid; i < 1056; i += 512) *(int4*)((char*)sS + (size_t)(3168 + i) * 16) = z;

    // A-frags for tap 0 (this wave's ohalf only): issued early
    bf16x8 Af[4], An[4];
#pragma unroll
    for (int ic = 0; ic < 4; ic++)
        Af[ic] = *(const bf16x8*)(Wt2 + (((size_t)(0 * 4 + ic) * 2 + ohalf) * 64 + lane) * 8);

    // ---- coalesced staging: thread = (w4 = tid&31, cg = tid>>5 -> 4 ch) ----
    {
        int w4 = tid & 31;
        int cg = tid >> 5;          // 0..15
        int c0 = cg * 4;
        int u8 = cg >> 1;           // 16B unit (8 channels)
        int hh = (cg & 1) * 4;      // shorts offset within unit
        const float* xp = x + ((size_t)(b * 64 + c0)) * 16384 + w4 * 4;

        int hgf = (h0 == 0) ? 0 : h0 - 1;         // first valid s-row
        int hm = (hgf == 0) ? 1 : hgf - 1;        // vertical reflect up
        float4 A[4], Bv[4], C[4];
#pragma unroll
        for (int cc = 0; cc < 4; cc++) {
            A[cc]  = *(const float4*)(xp + (size_t)cc * 16384 + (size_t)hm * 128);
            Bv[cc] = *(const float4*)(xp + (size_t)cc * 16384 + (size_t)hgf * 128);
            C[cc]  = *(const float4*)(xp + (size_t)cc * 16384 + (size_t)(hgf + 1) * 128);
        }

#pragma unroll
        for (int rr = 0; rr < 4; rr++) {
            int hg = h0 - 1 + rr;
            if (hg < 0 || hg > 127) continue;     // block-uniform skip (pre-zeroed)

            float4 Cn[4];
            if (rr < 3) {
                int hn = hg + 2;
                if (hn > 127) hn = 126;           // vertical reflect down
#pragma unroll
                for (int cc = 0; cc < 4; cc++)
                    Cn[cc] = *(const float4*)(xp + (size_t)cc * 16384 + (size_t)hn * 128);
            }

            unsigned short res[4][4];   // [cc][k]
#pragma unroll
            for (int cc = 0; cc < 4; cc++) {
                float4 vs;
                vs.x = A[cc].x + Bv[cc].x + C[cc].x;
                vs.y = A[cc].y + Bv[cc].y + C[cc].y;
                vs.z = A[cc].z + Bv[cc].z + C[cc].z;
                vs.w = A[cc].w + Bv[cc].w + C[cc].w;
                float L = __shfl_up(vs.w, 1, 32);
                float R = __shfl_down(vs.x, 1, 32);
                float sx = (w4 == 0) ? vs.x + 2.f * vs.y : L + vs.x + vs.y;
                float sy = vs.x + vs.y + vs.z;
                float sz = vs.y + vs.z + vs.w;
                float sw_ = (w4 == 31) ? 2.f * vs.z + vs.w : vs.z + vs.w + R;
                res[cc][0] = f2bf(sx);
                res[cc][1] = f2bf(sy);
                res[cc][2] = f2bf(sz);
                res[cc][3] = f2bf(sw_);
            }
            // write 4 ushort4 (4 channels = half a 16B unit) into swizzled slots
#pragma unroll
            for (int k = 0; k < 4; k++) {
                int slot = w4 * 4 + k + 1;        // w = w4*4+k -> slot w+1
                ushort4 o4 = make_ushort4(res[0][k], res[1][k], res[2][k], res[3][k]);
                *(ushort4*)(sS + (size_t)(rr * 132 + slot) * 64 + ((u8 ^ (slot & 7)) << 3) + hh) = o4;
            }
            if (rr < 3) {
#pragma unroll
                for (int cc = 0; cc < 4; cc++) { A[cc] = Bv[cc]; Bv[cc] = C[cc]; C[cc] = Cn[cc]; }
            }
        }
    }
    __syncthreads();

    // B LDS offsets (shorts) per (kx, ic); add (orow+ky)*8448 + nf*2048
    int p0[3][4];
#pragma unroll
    for (int kx = 0; kx < 3; kx++)
#pragma unroll
        for (int ic = 0; ic < 4; ic++) {
            int slot = n32 + kx + whalf * 64;
            int g = (ic * 2 + q2) ^ (slot & 7);   // (slot+64)&7 == slot&7
            p0[kx][ic] = slot * 64 + g * 8;
        }

    f32x16 acc[2];
#pragma unroll
    for (int nf = 0; nf < 2; nf++)
#pragma unroll
        for (int r = 0; r < 16; r++) acc[nf][r] = 0.f;

#pragma unroll
    for (int tap = 0; tap < 9; tap++) {
        int ky = tap / 3, kx = tap % 3;
        if (tap < 8) {
#pragma unroll
            for (int ic = 0; ic < 4; ic++)
                An[ic] = *(const bf16x8*)(Wt2 + (((size_t)((tap + 1) * 4 + ic) * 2 + ohalf) * 64 + lane) * 8);
        }
#pragma unroll
        for (int ic = 0; ic < 4; ic++) {
            const unsigned short* bp = sS + (size_t)(orow + ky) * 8448 + p0[kx][ic];
            bf16x8 b0 = *(const bf16x8*)(bp);
            bf16x8 b1 = *(const bf16x8*)(bp + 2048);
            acc[0] = __builtin_amdgcn_mfma_f32_32x32x16_bf16(Af[ic], b0, acc[0], 0, 0, 0);
            acc[1] = __builtin_amdgcn_mfma_f32_32x32x16_bf16(Af[ic], b1, acc[1], 0, 0, 0);
        }
        if (tap < 8) {
#pragma unroll
            for (int k = 0; k < 4; k++) Af[k] = An[k];
        }
    }

    // epilogue: 32x32 C/D layout col=lane&31 (pixel), row=(r&3)+8*(r>>2)+4*q2 (o)
    float* ob = out + ((size_t)b * 64) * 16384 + (size_t)(h0 + orow) * 128 + whalf * 64;
#pragma unroll
    for (int nf = 0; nf < 2; nf++)
#pragma unroll
        for (int r = 0; r < 16; r++) {
            int o = ohalf * 32 + (r & 3) + 8 * (r >> 2) + 4 * q2;
            ob[(size_t)o * 16384 + nf * 32 + n32] = acc[nf][r];
        }
}

// ---------------------------------------------------------------------------
extern "C" void kernel_launch(void* const* d_in, const int* in_sizes, int n_in,
                              void* d_out, int out_size, void* d_ws, size_t ws_size,
                              hipStream_t stream) {
    const float* x = (const float*)d_in[0];   // [16][64][128][128] fp32
    const float* W = (const float*)d_in[1];   // [64][64][3][3] fp32
    float* outp = (float*)d_out;

    // ws: Wt2 bf16 (73728 B); no global s intermediate
    unsigned short* Wt2 = (unsigned short*)d_ws;

    weff_kernel<<<2, 256, 0, stream>>>(W, Wt2);
    fused_kernel<<<1024, 512, 0, stream>>>(x, Wt2, outp);
}

// Round 9
// 136.404 us; speedup vs baseline: 1.0648x; 1.0349x over previous
//
#include <hip/hip_runtime.h>
#include <stdint.h>

// out = conv3x3_zeropad(s, W_eff), s = 3x3 reflect-pad box sum of x (B=16,C=64,H=W=128)
// R14: R13 structure (verified, 54.5us) + measured-waste removal:
//  (i)  double-XOR LDS swizzle p = u ^ (slot&7) ^ ((slot>>2)&7): kills the
//       16-way staging-write conflict (slot stride 4 made slot&7 2-valued);
//       B-read pattern unchanged (8/group is pigeonhole-inherent for b128);
//       +32/+64 slot offsets leave mapping invariant.
//  (ii) v_cvt_pk_bf16_f32 packing (RNE, bit-identical): 48->8 VALU/row-task.
//  (iii) tap-loop software pipeline: prefetch A + b0 frags one tap ahead;
//       b1 reads issued at tap start, hidden under acc[0] MFMAs.
//  (iv) XCD-aware block swizzle (bijective, 1024%8==0): contiguous strips
//       per XCD -> halo re-reads L2-hit.

#define THETA 0.7f

typedef __attribute__((ext_vector_type(8))) short bf16x8;
typedef __attribute__((ext_vector_type(16))) float f32x16;

__device__ inline unsigned short f2bf(float f) {
    unsigned u = __float_as_uint(f);
    u = (u + 0x7FFFu + ((u >> 16) & 1u)) >> 16;   // RNE
    return (unsigned short)u;
}
__device__ inline unsigned cvt_pk_bf16(float lo, float hi) {
    unsigned r;
    asm volatile("v_cvt_pk_bf16_f32 %0, %1, %2" : "=v"(r) : "v"(lo), "v"(hi));
    return r;   // lo16 = bf16(lo), hi16 = bf16(hi), RNE
}

// ---------------------------------------------------------------------------
// Kernel 1: W_eff -> Wt2 bf16, lane-contiguous MFMA-A layout (verified):
// Wt2[(((tap*4+ic)*2+mf)*64 + lane)*8 + j] = W_eff[o][ch][tap]
//   o = mf*32 + (lane&31), ch = ic*16 + (lane>>5)*8 + j
// ---------------------------------------------------------------------------
__global__ void weff_kernel(const float* __restrict__ W, unsigned short* __restrict__ Wt2) {
    int t = blockIdx.x * blockDim.x + threadIdx.x;   // 512 threads
    if (t >= 512) return;
    int o = t >> 3;
    int ch8 = t & 7;
    int c0 = ch8 * 8;
    int ic = ch8 >> 1;
    int mf = o >> 5;
    int lane = (o & 31) | ((ch8 & 1) << 5);

    float v[8][9];
    float tsum[8];
#pragma unroll
    for (int j = 0; j < 8; j++) {
        const float* w = W + ((size_t)o * 64 + c0 + j) * 9;
        float sum = 0.f;
#pragma unroll
        for (int k = 0; k < 9; k++) { v[j][k] = w[k]; sum += v[j][k]; }
        tsum[j] = sum;
    }
#pragma unroll
    for (int tap = 0; tap < 9; tap++) {
        unsigned short* dst = Wt2 + (((size_t)(tap * 4 + ic) * 2 + mf) * 64 + lane) * 8;
#pragma unroll
        for (int j = 0; j < 8; j++) {
            float val = v[j][tap] - ((tap == 4) ? THETA * tsum[j] : 0.f);
            dst[j] = f2bf(val);
        }
    }
}

// ---------------------------------------------------------------------------
// Kernel 2: fused boxsum + implicit-GEMM conv, mfma_f32_32x32x16_bf16.
// Block = (b, 2 out-rows, full 128 px), 512 thr / 8 waves; wave =
// (ohalf = wv>>2, orow = (wv>>1)&1, whalf = wv&1): 1 row x 64 px x 32 o,
// acc[2] of f32x16, 72 MFMA. LDS s-tile: [4 rows][132 slots][64 c] bf16 =
// 67584 B -> 2 blocks/CU = 16 waves/CU. slot = w+1 (slots 0/129 zero-pad);
// 16B units at p = u ^ (slot&7) ^ ((slot>>2)&7).
// Grid 1024 = 16 b x 64 strips, XCD-swizzled.
// ---------------------------------------------------------------------------
__global__ __launch_bounds__(512, 4) void fused_kernel(const float* __restrict__ x,
                                                       const unsigned short* __restrict__ Wt2,
                                                       float* __restrict__ out) {
    __shared__ __align__(16) unsigned short sS[4 * 132 * 64];   // 67584 B

    // XCD-aware bijective swizzle: 8 XCDs x 128 contiguous blocks
    int bid0 = blockIdx.x;
    int bid = (bid0 & 7) * 128 + (bid0 >> 3);
    int b = bid >> 6;
    int h0 = (bid & 63) * 2;
    int tid = threadIdx.x;
    int lane = tid & 63;
    int wv = tid >> 6;          // 0..7
    int n32 = lane & 31;
    int q2 = lane >> 5;
    int ohalf = wv >> 2;        // which 32 output channels
    int orow = (wv >> 1) & 1;   // out row within tile
    int whalf = wv & 1;         // which 64-px half

    // zero-pad slots 0 (w=-1) and 129 (w=128), rows 0..3: 64 x 16B
    int4 z = make_int4(0, 0, 0, 0);
    if (tid < 64) {
        int rr = tid >> 4;
        int sl = ((tid >> 3) & 1) ? 129 : 0;
        int g = tid & 7;
        *(int4*)((char*)sS + ((size_t)(rr * 132 + sl) * 8 + g) * 16) = z;
    }
    // zero OOB rows at image edges (staging skips them); row = 1056 int4
    if (h0 == 0)
        for (int i = tid; i < 1056; i += 512) *(int4*)((char*)sS + (size_t)i * 16) = z;
    if (h0 == 126)
        for (int i = tid; i < 1056; i += 512) *(int4*)((char*)sS + (size_t)(3168 + i) * 16) = z;

    // ---- coalesced staging: thread = (w4 = tid&31, cg = tid>>5 -> 4 ch) ----
    {
        int w4 = tid & 31;
        int cg = tid >> 5;          // 0..15
        int c0 = cg * 4;
        int u8 = cg >> 1;           // 16B unit (8 channels)
        int hh = (cg & 1) * 4;      // shorts offset within unit
        const float* xp = x + ((size_t)(b * 64 + c0)) * 16384 + w4 * 4;

        int hgf = (h0 == 0) ? 0 : h0 - 1;         // first valid s-row
        int hm = (hgf == 0) ? 1 : hgf - 1;        // vertical reflect up
        float4 A[4], Bv[4], C[4];
#pragma unroll
        for (int cc = 0; cc < 4; cc++) {
            A[cc]  = *(const float4*)(xp + (size_t)cc * 16384 + (size_t)hm * 128);
            Bv[cc] = *(const float4*)(xp + (size_t)cc * 16384 + (size_t)hgf * 128);
            C[cc]  = *(const float4*)(xp + (size_t)cc * 16384 + (size_t)(hgf + 1) * 128);
        }

#pragma unroll
        for (int rr = 0; rr < 4; rr++) {
            int hg = h0 - 1 + rr;
            if (hg < 0 || hg > 127) continue;     // block-uniform skip (pre-zeroed)

            float4 Cn[4];
            if (rr < 3) {
                int hn = hg + 2;
                if (hn > 127) hn = 126;           // vertical reflect down
#pragma unroll
                for (int cc = 0; cc < 4; cc++)
                    Cn[cc] = *(const float4*)(xp + (size_t)cc * 16384 + (size_t)hn * 128);
            }

            float rf[4][4];   // [cc][k]
#pragma unroll
            for (int cc = 0; cc < 4; cc++) {
                float4 vs;
                vs.x = A[cc].x + Bv[cc].x + C[cc].x;
                vs.y = A[cc].y + Bv[cc].y + C[cc].y;
                vs.z = A[cc].z + Bv[cc].z + C[cc].z;
                vs.w = A[cc].w + Bv[cc].w + C[cc].w;
                float L = __shfl_up(vs.w, 1, 32);
                float R = __shfl_down(vs.x, 1, 32);
                rf[cc][0] = (w4 == 0) ? vs.x + 2.f * vs.y : L + vs.x + vs.y;
                rf[cc][1] = vs.x + vs.y + vs.z;
                rf[cc][2] = vs.y + vs.z + vs.w;
                rf[cc][3] = (w4 == 31) ? 2.f * vs.z + vs.w : vs.z + vs.w + R;
            }
            // pack channel-major via cvt_pk, write 8B into double-XOR unit
#pragma unroll
            for (int k = 0; k < 4; k++) {
                int slot = w4 * 4 + k + 1;        // w = w4*4+k -> slot w+1
                uint2 o2 = make_uint2(cvt_pk_bf16(rf[0][k], rf[1][k]),
                                      cvt_pk_bf16(rf[2][k], rf[3][k]));
                int p = u8 ^ (slot & 7) ^ ((slot >> 2) & 7);
                *(uint2*)(sS + (size_t)(rr * 132 + slot) * 64 + (p << 3) + hh) = o2;
            }
            if (rr < 3) {
#pragma unroll
                for (int cc = 0; cc < 4; cc++) { A[cc] = Bv[cc]; Bv[cc] = C[cc]; C[cc] = Cn[cc]; }
            }
        }
    }
    __syncthreads();

    // B LDS offsets (shorts) per (kx, ic); add (orow+ky)*8448, b1 = +2048
    // mapping invariant under slot+32 / slot+64 -> nf/whalf offsets legal
    int p0[3][4];
#pragma unroll
    for (int kx = 0; kx < 3; kx++)
#pragma unroll
        for (int ic = 0; ic < 4; ic++) {
            int slot = n32 + kx + whalf * 64;
            int g = (ic * 2 + q2) ^ (slot & 7) ^ ((slot >> 2) & 7);
            p0[kx][ic] = slot * 64 + g * 8;
        }

    f32x16 acc[2];
#pragma unroll
    for (int nf = 0; nf < 2; nf++)
#pragma unroll
        for (int r = 0; r < 16; r++) acc[nf][r] = 0.f;

    // ---- software-pipelined tap loop ----
    bf16x8 Af[4], An[4], B0[4], B0n[4], B1[4];
#pragma unroll
    for (int ic = 0; ic < 4; ic++) {
        Af[ic] = *(const bf16x8*)(Wt2 + (((size_t)(0 * 4 + ic) * 2 + ohalf) * 64 + lane) * 8);
        B0[ic] = *(const bf16x8*)(sS + (size_t)(orow + 0) * 8448 + p0[0][ic]);
    }

#pragma unroll
    for (int tap = 0; tap < 9; tap++) {
        int ky = tap / 3, kx = tap % 3;
        const unsigned short* brow = sS + (size_t)(orow + ky) * 8448;
        // issue b1 reads for current tap (hidden under acc[0] MFMAs)
#pragma unroll
        for (int ic = 0; ic < 4; ic++)
            B1[ic] = *(const bf16x8*)(brow + p0[kx][ic] + 2048);
        // prefetch next tap: b0 frags + A frags
        if (tap < 8) {
            int kyn = (tap + 1) / 3, kxn = (tap + 1) % 3;
            const unsigned short* brn = sS + (size_t)(orow + kyn) * 8448;
#pragma unroll
            for (int ic = 0; ic < 4; ic++) {
                B0n[ic] = *(const bf16x8*)(brn + p0[kxn][ic]);
                An[ic] = *(const bf16x8*)(Wt2 + (((size_t)((tap + 1) * 4 + ic) * 2 + ohalf) * 64 + lane) * 8);
            }
        }
#pragma unroll
        for (int ic = 0; ic < 4; ic++)
            acc[0] = __builtin_amdgcn_mfma_f32_32x32x16_bf16(Af[ic], B0[ic], acc[0], 0, 0, 0);
#pragma unroll
        for (int ic = 0; ic < 4; ic++)
            acc[1] = __builtin_amdgcn_mfma_f32_32x32x16_bf16(Af[ic], B1[ic], acc[1], 0, 0, 0);
        if (tap < 8) {
#pragma unroll
            for (int k = 0; k < 4; k++) { Af[k] = An[k]; B0[k] = B0n[k]; }
        }
    }

    // epilogue: 32x32 C/D layout col=lane&31 (pixel), row=(r&3)+8*(r>>2)+4*q2 (o)
    float* ob = out + ((size_t)b * 64) * 16384 + (size_t)(h0 + orow) * 128 + whalf * 64;
#pragma unroll
    for (int nf = 0; nf < 2; nf++)
#pragma unroll
        for (int r = 0; r < 16; r++) {
            int o = ohalf * 32 + (r & 3) + 8 * (r >> 2) + 4 * q2;
            ob[(size_t)o * 16384 + nf * 32 + n32] = acc[nf][r];
        }
}

// ---------------------------------------------------------------------------
extern "C" void kernel_launch(void* const* d_in, const int* in_sizes, int n_in,
                              void* d_out, int out_size, void* d_ws, size_t ws_size,
                              hipStream_t stream) {
    const float* x = (const float*)d_in[0];   // [16][64][128][128] fp32
    const float* W = (const float*)d_in[1];   // [64][64][3][3] fp32
    float* outp = (float*)d_out;

    // ws: Wt2 bf16 (73728 B); no global s intermediate
    unsigned short* Wt2 = (unsigned short*)d_ws;

    weff_kernel<<<2, 256, 0, stream>>>(W, Wt2);
    fused_kernel<<<1024, 512, 0, stream>>>(x, Wt2, outp);
}